// Round 8
// baseline (933.743 us; speedup 1.0000x reference)
//
#include <hip/hip_runtime.h>
#include <hip/hip_bf16.h>

#define N_NODES 100000
#define N_PAIRS 1600000
#define EDGE_NUM 30000
#define D 64
#define NEG_SLOPE 0.2f

#define ERANGE (EDGE_NUM / 8)   // 3750
#define VRANGE (N_NODES / 8)    // 12500
#define SCAP   208000           // per-bucket stream capacity (expected 200k)
#define BINB   768              // binA grid
#define BCAP   384              // LDS entries per bucket (flush at >=128)
#define PBG    64               // groups per (which,range) in fillB

// ---------------------------------------------------------------------------
// X (f32) -> Xbf (bf16), vectorized
// ---------------------------------------------------------------------------
__global__ __launch_bounds__(256) void xbf_kernel(
    const float* __restrict__ X, __hip_bfloat16* __restrict__ Xbf)
{
    const int i = (blockIdx.x * 256 + threadIdx.x) * 4;
    if (i < N_NODES * D) {
        float4 f = *(const float4*)&X[i];
        __hip_bfloat16 h[4] = {__float2bfloat16(f.x), __float2bfloat16(f.y),
                               __float2bfloat16(f.z), __float2bfloat16(f.w)};
        *(ushort4*)&Xbf[i] = *(const ushort4*)h;
    }
}

// ---------------------------------------------------------------------------
// Pass A: histogram + bin (key,partner) into 16 append-only streams.
// LDS buckets flushed with one global-atomic reservation + dense writes.
// ---------------------------------------------------------------------------
__global__ __launch_bounds__(256) void bin_kernel(
    const int* __restrict__ edges, const int* __restrict__ vertex,
    int* __restrict__ ecnt, int* __restrict__ vcnt,
    int2* __restrict__ streamE, int2* __restrict__ streamV,
    int* __restrict__ gcnt)                 // [16]: 0..7 = E, 8..15 = V
{
    __shared__ int2 buf[16][BCAP];          // 48 KB
    __shared__ int bcnt[16];
    __shared__ int bbase[16];
    if (threadIdx.x < 16) bcnt[threadIdx.x] = 0;
    __syncthreads();

    const int per_block = (N_PAIRS + BINB - 1) / BINB;
    const int p0 = blockIdx.x * per_block;
    const int p1 = min(p0 + per_block, N_PAIRS);

    for (int base = p0; base < p1; base += 256) {
        const int i = base + threadIdx.x;
        if (i < p1) {
            const int e = edges[i];
            const int v = vertex[i];
            atomicAdd(&ecnt[e], 1);
            atomicAdd(&vcnt[v], 1);
            const int eb = e / ERANGE;
            const int vb = 8 + v / VRANGE;
            int s = atomicAdd(&bcnt[eb], 1);
            buf[eb][s] = make_int2(e, v);
            s = atomicAdd(&bcnt[vb], 1);
            buf[vb][s] = make_int2(v, e);
        }
        __syncthreads();
        for (int b = 0; b < 16; ++b) {
            const int c = bcnt[b];          // uniform post-barrier
            if (c >= 128) {
                if (threadIdx.x == 0) bbase[b] = atomicAdd(&gcnt[b], c);
                __syncthreads();
                const int gb = bbase[b];
                int2* dst = (b < 8) ? (streamE + (size_t)b * SCAP)
                                    : (streamV + (size_t)(b - 8) * SCAP);
                for (int k = threadIdx.x; k < c; k += 256)
                    if (gb + k < SCAP) dst[gb + k] = buf[b][k];
                __syncthreads();
                if (threadIdx.x == 0) bcnt[b] = 0;
                __syncthreads();
            }
        }
    }
    // final flush
    for (int b = 0; b < 16; ++b) {
        const int c = bcnt[b];
        if (c > 0) {
            if (threadIdx.x == 0) bbase[b] = atomicAdd(&gcnt[b], c);
            __syncthreads();
            const int gb = bbase[b];
            int2* dst = (b < 8) ? (streamE + (size_t)b * SCAP)
                                : (streamV + (size_t)(b - 8) * SCAP);
            for (int k = threadIdx.x; k < c; k += 256)
                if (gb + k < SCAP) dst[gb + k] = buf[b][k];
            __syncthreads();
            if (threadIdx.x == 0) bcnt[b] = 0;
            __syncthreads();
        }
    }
}

// ---------------------------------------------------------------------------
// scan: 16 elements/thread/chunk exclusive prefix
// ---------------------------------------------------------------------------
__device__ void scan_body(const int* cnt, int* off, int* cur, int n)
{
    __shared__ int wsum[16];
    __shared__ int s_carry;
    if (threadIdx.x == 0) s_carry = 0;
    __syncthreads();
    const int lane = threadIdx.x & 63;
    const int wave = threadIdx.x >> 6;

    for (int base = 0; base < n; base += 16384) {
        const int i0 = base + threadIdx.x * 16;
        int x[16];
        #pragma unroll
        for (int q = 0; q < 4; ++q) {
            const int ii = i0 + q * 4;
            if (ii + 3 < n) {
                int4 t = *(const int4*)&cnt[ii];
                x[q*4] = t.x; x[q*4+1] = t.y; x[q*4+2] = t.z; x[q*4+3] = t.w;
            } else {
                #pragma unroll
                for (int r = 0; r < 4; ++r) x[q*4+r] = (ii + r < n) ? cnt[ii + r] : 0;
            }
        }
        int tsum = 0;
        #pragma unroll
        for (int q = 0; q < 16; ++q) tsum += x[q];
        int sc = tsum;
        #pragma unroll
        for (int s = 1; s < 64; s <<= 1) {
            int y = __shfl_up(sc, s);
            if (lane >= s) sc += y;
        }
        if (lane == 63) wsum[wave] = sc;
        __syncthreads();
        int wbase = 0;
        for (int w = 0; w < wave; ++w) wbase += wsum[w];
        const int carry = s_carry;
        int run = carry + wbase + sc - tsum;
        int y[16];
        #pragma unroll
        for (int q = 0; q < 16; ++q) { y[q] = run; run += x[q]; }
        #pragma unroll
        for (int q = 0; q < 4; ++q) {
            const int ii = i0 + q * 4;
            if (ii + 3 < n) {
                *(int4*)&off[ii] = make_int4(y[q*4], y[q*4+1], y[q*4+2], y[q*4+3]);
                *(int4*)&cur[ii] = make_int4(y[q*4], y[q*4+1], y[q*4+2], y[q*4+3]);
            } else {
                #pragma unroll
                for (int r = 0; r < 4; ++r)
                    if (ii + r < n) { off[ii+r] = y[q*4+r]; cur[ii+r] = y[q*4+r]; }
            }
        }
        __syncthreads();
        if (threadIdx.x == 1023) s_carry = carry + wbase + sc;
        __syncthreads();
    }
    if (threadIdx.x == 0) off[n] = s_carry;
}

__global__ __launch_bounds__(1024) void scan2_kernel(
    int* ecnt, int* eoff, int* vcnt, int* voff)
{
    if (blockIdx.x == 0) scan_body(ecnt, eoff, ecnt, EDGE_NUM);
    else                 scan_body(vcnt, voff, vcnt, N_NODES);
}

// ---------------------------------------------------------------------------
// Pass B: XCD-pinned scatter from local dense streams into CSR lists.
// XCD r handles e-range r and v-range r: reads 2x1.6 MB local streams,
// writes 2x0.8 MB local CSR windows -> everything L2-resident.
// ---------------------------------------------------------------------------
__global__ __launch_bounds__(256) void fillB_kernel(
    const int2* __restrict__ streamE, const int2* __restrict__ streamV,
    const int* __restrict__ gcnt,
    int* __restrict__ ecur, int* __restrict__ vcur,
    int* __restrict__ evlist, int* __restrict__ velist)
{
    const int r = blockIdx.x & 7;
    const int which = (blockIdx.x >> 3) & 1;
    const int grp = blockIdx.x >> 4;
    const int2* src; int n; int* cur; int* outl;
    if (which == 0) { src = streamE + (size_t)r * SCAP; n = min(gcnt[r],     SCAP); cur = ecur; outl = evlist; }
    else            { src = streamV + (size_t)r * SCAP; n = min(gcnt[8 + r], SCAP); cur = vcur; outl = velist; }
    for (int i = grp * 256 + threadIdx.x; i < n; i += PBG * 256) {
        const int2 p = src[i];
        outl[atomicAdd(&cur[p.x], 1)] = p.y;
    }
}

// ---------------------------------------------------------------------------
// Per-edge gather (bf16 X), pipelined 8-batches; bf16 Xe output.
// ---------------------------------------------------------------------------
__global__ __launch_bounds__(256) void edge_gather_kernel(
    const __hip_bfloat16* __restrict__ Xbf, const float* __restrict__ degV,
    const float* __restrict__ Ww, const float* __restrict__ Wb,
    const int* __restrict__ eoff, const int* __restrict__ evlist,
    __hip_bfloat16* __restrict__ Xe)
{
    const int lane = threadIdx.x & 63;
    const int wave = threadIdx.x >> 6;
    const int e = blockIdx.x * 4 + wave;
    const int t = (e >= 10000) + (e >= 20000);   // uniform per block

    const int start = eoff[e], end = eoff[e + 1];
    const float* __restrict__ degt = degV + (size_t)t * N_NODES;
    const __hip_bfloat16* __restrict__ Xl = Xbf + lane;

    float acc0 = 0.f, acc1 = 0.f, sdeg = 0.f;
    for (int j0 = start; j0 < end; j0 += 64) {
        const int m = min(64, end - j0);
        const int vv = (lane < m) ? evlist[j0 + lane] : 0;
        const int nb = (m + 7) >> 3;
        int vc[8]; float fc[8], sc[8];
        #pragma unroll
        for (int u = 0; u < 8; ++u) vc[u] = __shfl(vv, u);
        #pragma unroll
        for (int u = 0; u < 8; ++u) fc[u] = __bfloat162float(Xl[(size_t)vc[u] * D]);
        #pragma unroll
        for (int u = 0; u < 8; ++u) sc[u] = (u < m) ? degt[vc[u]] : 0.f;
        for (int bi = 0; bi < nb; ++bi) {
            const int jn = bi * 8 + 8;
            const bool more = (bi + 1 < nb);
            int vn[8]; float fn[8], sn[8];
            if (more) {
                #pragma unroll
                for (int u = 0; u < 8; ++u) vn[u] = __shfl(vv, jn + u);
                #pragma unroll
                for (int u = 0; u < 8; ++u) fn[u] = __bfloat162float(Xl[(size_t)vn[u] * D]);
                #pragma unroll
                for (int u = 0; u < 8; ++u) sn[u] = (jn + u < m) ? degt[vn[u]] : 0.f;
            }
            #pragma unroll
            for (int u = 0; u < 8; u += 2) {
                acc0 = fmaf(sc[u],     fc[u],     acc0);
                acc1 = fmaf(sc[u + 1], fc[u + 1], acc1);
                sdeg += sc[u] + sc[u + 1];
            }
            if (more) {
                #pragma unroll
                for (int u = 0; u < 8; ++u) { vc[u]=vn[u]; fc[u]=fn[u]; sc[u]=sn[u]; }
            }
        }
    }
    const float acc = acc0 + acc1;

    float w[64];
    const float* wrow = Ww + ((size_t)(t + 1) * 64 + lane) * 64;
    #pragma unroll
    for (int i = 0; i < 64; i += 4) {
        float4 v = *(const float4*)(wrow + i);
        w[i] = v.x; w[i+1] = v.y; w[i+2] = v.z; w[i+3] = v.w;
    }
    float r = 0.f;
    #pragma unroll
    for (int i = 0; i < 64; ++i) r = fmaf(__shfl(acc, i), w[i], r);
    r += sdeg * Wb[(t + 1) * 64 + lane];
    const int k = max(end - start, 1);
    Xe[(size_t)e * D + lane] = __float2bfloat16(r / (float)k);
}

// ---------------------------------------------------------------------------
// Per-vertex: pipelined bf16-Xe gather (3.84 MB -> L2-resident) + fused X0
// matvec epilogue (f32 X) + L2 norm + leaky relu.
// ---------------------------------------------------------------------------
__global__ __launch_bounds__(256) void vertex_gather_kernel(
    const float* __restrict__ X, const float* __restrict__ Ww,
    const float* __restrict__ Wb, const __hip_bfloat16* __restrict__ Xe,
    const int* __restrict__ voff, const int* __restrict__ velist,
    float* __restrict__ out)
{
    const int v = blockIdx.x * 4 + (threadIdx.x >> 6);
    const int lane = threadIdx.x & 63;
    const int start = voff[v], end = voff[v + 1];
    const __hip_bfloat16* __restrict__ Xel = Xe + lane;

    float acc0 = 0.f, acc1 = 0.f;
    for (int j0 = start; j0 < end; j0 += 64) {
        const int m = min(64, end - j0);
        const int ee = (lane < m) ? velist[j0 + lane] : 0;
        const int nb = (m + 7) >> 3;
        int ec[8]; float fc[8], mc[8];
        #pragma unroll
        for (int u = 0; u < 8; ++u) ec[u] = __shfl(ee, u);
        #pragma unroll
        for (int u = 0; u < 8; ++u) fc[u] = __bfloat162float(Xel[(size_t)ec[u] * D]);
        #pragma unroll
        for (int u = 0; u < 8; ++u) mc[u] = (u < m) ? 1.f : 0.f;
        for (int bi = 0; bi < nb; ++bi) {
            const int jn = bi * 8 + 8;
            const bool more = (bi + 1 < nb);
            int en[8]; float fn[8], mn[8];
            if (more) {
                #pragma unroll
                for (int u = 0; u < 8; ++u) en[u] = __shfl(ee, jn + u);
                #pragma unroll
                for (int u = 0; u < 8; ++u) fn[u] = __bfloat162float(Xel[(size_t)en[u] * D]);
                #pragma unroll
                for (int u = 0; u < 8; ++u) mn[u] = (jn + u < m) ? 1.f : 0.f;
            }
            #pragma unroll
            for (int u = 0; u < 8; u += 2) {
                acc0 = fmaf(mc[u],     fc[u],     acc0);
                acc1 = fmaf(mc[u + 1], fc[u + 1], acc1);
            }
            if (more) {
                #pragma unroll
                for (int u = 0; u < 8; ++u) { ec[u]=en[u]; fc[u]=fn[u]; mc[u]=mn[u]; }
            }
        }
    }

    float w[64];
    const float* wrow = Ww + (size_t)lane * 64;
    #pragma unroll
    for (int i = 0; i < 64; i += 4) {
        float4 t4 = *(const float4*)(wrow + i);
        w[i] = t4.x; w[i+1] = t4.y; w[i+2] = t4.z; w[i+3] = t4.w;
    }
    const float xr = X[(size_t)v * D + lane];
    float x0 = 0.f;
    #pragma unroll
    for (int i = 0; i < 64; ++i) x0 = fmaf(__shfl(xr, i), w[i], x0);

    const float acc = (acc0 + acc1) + (x0 + Wb[lane]);

    float ss = acc * acc;
    #pragma unroll
    for (int off = 1; off < 64; off <<= 1) ss += __shfl_xor(ss, off);
    const float rn = sqrtf(ss);
    const float scale = (rn == 0.f) ? 0.f : 1.f / rn;
    const float y = acc * scale;
    out[(size_t)v * D + lane] = (y > 0.f) ? y : NEG_SLOPE * y;
}

// ---------------------------------------------------------------------------
extern "C" void kernel_launch(void* const* d_in, const int* in_sizes, int n_in,
                              void* d_out, int out_size, void* d_ws, size_t ws_size,
                              hipStream_t stream)
{
    const float* X      = (const float*)d_in[0];
    const float* degV   = (const float*)d_in[1];
    const float* Ww     = (const float*)d_in[2];
    const float* Wb     = (const float*)d_in[3];
    const int*   vertex = (const int*)d_in[4];
    const int*   edges  = (const int*)d_in[5];
    float* out = (float*)d_out;

    // workspace layout (~57.1 MB)
    char* p = (char*)d_ws;
    __hip_bfloat16* Xe  = (__hip_bfloat16*)p;  p += (size_t)EDGE_NUM * D * 2;   // 3.84 MB
    __hip_bfloat16* Xbf = (__hip_bfloat16*)p;  p += (size_t)N_NODES * D * 2;    // 12.8 MB
    int* ib     = (int*)p;
    int* eoff   = ib;                  // 30004
    int* ecur   = ib + 30004;          // 30004
    int* voff   = ib + 60008;          // 100004
    int* vcur   = ib + 160012;         // 100004
    int* gcnt   = ib + 260016;         // 16
    p += (size_t)260032 * 4;
    int2* streamE = (int2*)p;          p += (size_t)8 * SCAP * 8;               // 13.3 MB
    int2* streamV = (int2*)p;          p += (size_t)8 * SCAP * 8;               // 13.3 MB
    int* evlist   = (int*)p;           p += (size_t)N_PAIRS * 4;
    int* velist   = (int*)p;

    // zero counters (ecur, vcur, gcnt; eoff/voff harmlessly included)
    hipMemsetAsync(ib, 0, (size_t)260032 * 4, stream);

    xbf_kernel<<<(N_NODES * D / 4 + 255) / 256, 256, 0, stream>>>(X, Xbf);

    bin_kernel<<<BINB, 256, 0, stream>>>(edges, vertex, ecur, vcur,
                                         streamE, streamV, gcnt);

    scan2_kernel<<<2, 1024, 0, stream>>>(ecur, eoff, vcur, voff);

    fillB_kernel<<<16 * PBG, 256, 0, stream>>>(streamE, streamV, gcnt,
                                               ecur, vcur, evlist, velist);

    edge_gather_kernel<<<EDGE_NUM / 4, 256, 0, stream>>>(
        Xbf, degV, Ww, Wb, eoff, evlist, Xe);

    vertex_gather_kernel<<<N_NODES / 4, 256, 0, stream>>>(
        X, Ww, Wb, Xe, voff, velist, out);
}

// Round 9
// 685.583 us; speedup vs baseline: 1.3620x; 1.3620x over previous
//
#include <hip/hip_runtime.h>
#include <hip/hip_bf16.h>

#define N_NODES 100000
#define N_PAIRS 1600000
#define EDGE_NUM 30000
#define D 64
#define NEG_SLOPE 0.2f
#define NG 128  // pair-chunks for the XCD-pinned fill (grid = 8*NG)

// ---------------------------------------------------------------------------
// Prelude: fused histograms + X(f32)->Xbf(bf16) conversion.
// Grid 6250 x 256 covers both index spaces exactly (1.6M pairs; 1.6M float4).
// ---------------------------------------------------------------------------
__global__ __launch_bounds__(256) void prelude_kernel(
    const int* __restrict__ edges, const int* __restrict__ vertex,
    const float* __restrict__ X, __hip_bfloat16* __restrict__ Xbf,
    int* __restrict__ ecnt, int* __restrict__ vcnt)
{
    const int i = blockIdx.x * 256 + threadIdx.x;
    if (i < N_PAIRS) {
        atomicAdd(&ecnt[edges[i]], 1);
        atomicAdd(&vcnt[vertex[i]], 1);
    }
    const int c = i * 4;
    if (c < N_NODES * D) {
        float4 f = *(const float4*)&X[c];
        __hip_bfloat16 h[4] = {__float2bfloat16(f.x), __float2bfloat16(f.y),
                               __float2bfloat16(f.z), __float2bfloat16(f.w)};
        *(ushort4*)&Xbf[c] = *(const ushort4*)h;
    }
}

// ---------------------------------------------------------------------------
// scan: 16 elements/thread/chunk exclusive prefix
// ---------------------------------------------------------------------------
__device__ void scan_body(const int* cnt, int* off, int* cur, int n)
{
    __shared__ int wsum[16];
    __shared__ int s_carry;
    if (threadIdx.x == 0) s_carry = 0;
    __syncthreads();
    const int lane = threadIdx.x & 63;
    const int wave = threadIdx.x >> 6;

    for (int base = 0; base < n; base += 16384) {
        const int i0 = base + threadIdx.x * 16;
        int x[16];
        #pragma unroll
        for (int q = 0; q < 4; ++q) {
            const int ii = i0 + q * 4;
            if (ii + 3 < n) {
                int4 t = *(const int4*)&cnt[ii];
                x[q*4] = t.x; x[q*4+1] = t.y; x[q*4+2] = t.z; x[q*4+3] = t.w;
            } else {
                #pragma unroll
                for (int r = 0; r < 4; ++r) x[q*4+r] = (ii + r < n) ? cnt[ii + r] : 0;
            }
        }
        int tsum = 0;
        #pragma unroll
        for (int q = 0; q < 16; ++q) tsum += x[q];
        int sc = tsum;
        #pragma unroll
        for (int s = 1; s < 64; s <<= 1) {
            int y = __shfl_up(sc, s);
            if (lane >= s) sc += y;
        }
        if (lane == 63) wsum[wave] = sc;
        __syncthreads();
        int wbase = 0;
        for (int w = 0; w < wave; ++w) wbase += wsum[w];
        const int carry = s_carry;
        int run = carry + wbase + sc - tsum;
        int y[16];
        #pragma unroll
        for (int q = 0; q < 16; ++q) { y[q] = run; run += x[q]; }
        #pragma unroll
        for (int q = 0; q < 4; ++q) {
            const int ii = i0 + q * 4;
            if (ii + 3 < n) {
                *(int4*)&off[ii] = make_int4(y[q*4], y[q*4+1], y[q*4+2], y[q*4+3]);
                *(int4*)&cur[ii] = make_int4(y[q*4], y[q*4+1], y[q*4+2], y[q*4+3]);
            } else {
                #pragma unroll
                for (int r = 0; r < 4; ++r)
                    if (ii + r < n) { off[ii+r] = y[q*4+r]; cur[ii+r] = y[q*4+r]; }
            }
        }
        __syncthreads();
        if (threadIdx.x == 1023) s_carry = carry + wbase + sc;
        __syncthreads();
    }
    if (threadIdx.x == 0) off[n] = s_carry;
}

__global__ __launch_bounds__(1024) void scan2_kernel(
    int* ecnt, int* eoff, int* vcnt, int* voff)
{
    if (blockIdx.x == 0) scan_body(ecnt, eoff, ecnt, EDGE_NUM);
    else                 scan_body(vcnt, voff, vcnt, N_NODES);
}

// XCD-pinned fill (blockIdx%8 -> XCD): each XCD owns one key range, so its
// ~1.6 MB CSR write set stays in its own L2 (measured: 198->153 MB WRITE).
__global__ __launch_bounds__(256) void fill_xcd_kernel(
    const int* __restrict__ edges, const int* __restrict__ vertex,
    int* __restrict__ ecur, int* __restrict__ vcur,
    int* __restrict__ evlist, int* __restrict__ velist)
{
    const int xcd = blockIdx.x & 7;
    const int grp = blockIdx.x >> 3;
    const int elo = xcd * (EDGE_NUM / 8);
    const int ehi = elo + (EDGE_NUM / 8);
    const int vlo = xcd * (N_NODES / 8);
    const int vhi = vlo + (N_NODES / 8);

    for (int i = grp * 256 + threadIdx.x; i < N_PAIRS; i += NG * 256) {
        const int e = edges[i];
        const int v = vertex[i];
        if (e >= elo && e < ehi) evlist[atomicAdd(&ecur[e], 1)] = v;
        if (v >= vlo && v < vhi) velist[atomicAdd(&vcur[v], 1)] = e;
    }
}

// ---------------------------------------------------------------------------
// Per-edge gather (bf16 X, 128 B/row), pipelined 8-batches; bf16 Xe output.
// ---------------------------------------------------------------------------
__global__ __launch_bounds__(256) void edge_gather_kernel(
    const __hip_bfloat16* __restrict__ Xbf, const float* __restrict__ degV,
    const float* __restrict__ Ww, const float* __restrict__ Wb,
    const int* __restrict__ eoff, const int* __restrict__ evlist,
    __hip_bfloat16* __restrict__ Xe)
{
    const int lane = threadIdx.x & 63;
    const int wave = threadIdx.x >> 6;
    const int e = blockIdx.x * 4 + wave;
    const int t = (e >= 10000) + (e >= 20000);   // uniform per block

    const int start = eoff[e], end = eoff[e + 1];
    const float* __restrict__ degt = degV + (size_t)t * N_NODES;
    const __hip_bfloat16* __restrict__ Xl = Xbf + lane;

    float acc0 = 0.f, acc1 = 0.f, sdeg = 0.f;
    for (int j0 = start; j0 < end; j0 += 64) {
        const int m = min(64, end - j0);
        const int vv = (lane < m) ? evlist[j0 + lane] : 0;
        const int nb = (m + 7) >> 3;
        int vc[8]; float fc[8], sc[8];
        #pragma unroll
        for (int u = 0; u < 8; ++u) vc[u] = __shfl(vv, u);
        #pragma unroll
        for (int u = 0; u < 8; ++u) fc[u] = __bfloat162float(Xl[(size_t)vc[u] * D]);
        #pragma unroll
        for (int u = 0; u < 8; ++u) sc[u] = (u < m) ? degt[vc[u]] : 0.f;
        for (int bi = 0; bi < nb; ++bi) {
            const int jn = bi * 8 + 8;
            const bool more = (bi + 1 < nb);
            int vn[8]; float fn[8], sn[8];
            if (more) {
                #pragma unroll
                for (int u = 0; u < 8; ++u) vn[u] = __shfl(vv, jn + u);
                #pragma unroll
                for (int u = 0; u < 8; ++u) fn[u] = __bfloat162float(Xl[(size_t)vn[u] * D]);
                #pragma unroll
                for (int u = 0; u < 8; ++u) sn[u] = (jn + u < m) ? degt[vn[u]] : 0.f;
            }
            #pragma unroll
            for (int u = 0; u < 8; u += 2) {
                acc0 = fmaf(sc[u],     fc[u],     acc0);
                acc1 = fmaf(sc[u + 1], fc[u + 1], acc1);
                sdeg += sc[u] + sc[u + 1];
            }
            if (more) {
                #pragma unroll
                for (int u = 0; u < 8; ++u) { vc[u]=vn[u]; fc[u]=fn[u]; sc[u]=sn[u]; }
            }
        }
    }
    const float acc = acc0 + acc1;

    float w[64];
    const float* wrow = Ww + ((size_t)(t + 1) * 64 + lane) * 64;
    #pragma unroll
    for (int i = 0; i < 64; i += 4) {
        float4 v = *(const float4*)(wrow + i);
        w[i] = v.x; w[i+1] = v.y; w[i+2] = v.z; w[i+3] = v.w;
    }
    float r = 0.f;
    #pragma unroll
    for (int i = 0; i < 64; ++i) r = fmaf(__shfl(acc, i), w[i], r);
    r += sdeg * Wb[(t + 1) * 64 + lane];
    const int k = max(end - start, 1);
    Xe[(size_t)e * D + lane] = __float2bfloat16(r / (float)k);
}

// ---------------------------------------------------------------------------
// Per-vertex: pipelined bf16-Xe gather (3.84 MB < 4 MiB/XCD L2 -> hits) +
// fused X0 matvec epilogue (f32 X) + L2 norm + leaky relu.
// ---------------------------------------------------------------------------
__global__ __launch_bounds__(256) void vertex_gather_kernel(
    const float* __restrict__ X, const float* __restrict__ Ww,
    const float* __restrict__ Wb, const __hip_bfloat16* __restrict__ Xe,
    const int* __restrict__ voff, const int* __restrict__ velist,
    float* __restrict__ out)
{
    const int v = blockIdx.x * 4 + (threadIdx.x >> 6);
    const int lane = threadIdx.x & 63;
    const int start = voff[v], end = voff[v + 1];
    const __hip_bfloat16* __restrict__ Xel = Xe + lane;

    float acc0 = 0.f, acc1 = 0.f;
    for (int j0 = start; j0 < end; j0 += 64) {
        const int m = min(64, end - j0);
        const int ee = (lane < m) ? velist[j0 + lane] : 0;
        const int nb = (m + 7) >> 3;
        int ec[8]; float fc[8], mc[8];
        #pragma unroll
        for (int u = 0; u < 8; ++u) ec[u] = __shfl(ee, u);
        #pragma unroll
        for (int u = 0; u < 8; ++u) fc[u] = __bfloat162float(Xel[(size_t)ec[u] * D]);
        #pragma unroll
        for (int u = 0; u < 8; ++u) mc[u] = (u < m) ? 1.f : 0.f;
        for (int bi = 0; bi < nb; ++bi) {
            const int jn = bi * 8 + 8;
            const bool more = (bi + 1 < nb);
            int en[8]; float fn[8], mn[8];
            if (more) {
                #pragma unroll
                for (int u = 0; u < 8; ++u) en[u] = __shfl(ee, jn + u);
                #pragma unroll
                for (int u = 0; u < 8; ++u) fn[u] = __bfloat162float(Xel[(size_t)en[u] * D]);
                #pragma unroll
                for (int u = 0; u < 8; ++u) mn[u] = (jn + u < m) ? 1.f : 0.f;
            }
            #pragma unroll
            for (int u = 0; u < 8; u += 2) {
                acc0 = fmaf(mc[u],     fc[u],     acc0);
                acc1 = fmaf(mc[u + 1], fc[u + 1], acc1);
            }
            if (more) {
                #pragma unroll
                for (int u = 0; u < 8; ++u) { ec[u]=en[u]; fc[u]=fn[u]; mc[u]=mn[u]; }
            }
        }
    }

    float w[64];
    const float* wrow = Ww + (size_t)lane * 64;
    #pragma unroll
    for (int i = 0; i < 64; i += 4) {
        float4 t4 = *(const float4*)(wrow + i);
        w[i] = t4.x; w[i+1] = t4.y; w[i+2] = t4.z; w[i+3] = t4.w;
    }
    const float xr = X[(size_t)v * D + lane];
    float x0 = 0.f;
    #pragma unroll
    for (int i = 0; i < 64; ++i) x0 = fmaf(__shfl(xr, i), w[i], x0);

    const float acc = (acc0 + acc1) + (x0 + Wb[lane]);

    float ss = acc * acc;
    #pragma unroll
    for (int off = 1; off < 64; off <<= 1) ss += __shfl_xor(ss, off);
    const float rn = sqrtf(ss);
    const float scale = (rn == 0.f) ? 0.f : 1.f / rn;
    const float y = acc * scale;
    out[(size_t)v * D + lane] = (y > 0.f) ? y : NEG_SLOPE * y;
}

// ---------------------------------------------------------------------------
extern "C" void kernel_launch(void* const* d_in, const int* in_sizes, int n_in,
                              void* d_out, int out_size, void* d_ws, size_t ws_size,
                              hipStream_t stream)
{
    const float* X      = (const float*)d_in[0];
    const float* degV   = (const float*)d_in[1];
    const float* Ww     = (const float*)d_in[2];
    const float* Wb     = (const float*)d_in[3];
    const int*   vertex = (const int*)d_in[4];
    const int*   edges  = (const int*)d_in[5];
    float* out = (float*)d_out;

    // workspace layout (~30.5 MB)
    char* p = (char*)d_ws;
    __hip_bfloat16* Xe  = (__hip_bfloat16*)p;  p += (size_t)EDGE_NUM * D * 2;   // 3.84 MB
    __hip_bfloat16* Xbf = (__hip_bfloat16*)p;  p += (size_t)N_NODES * D * 2;    // 12.8 MB
    int* ib     = (int*)p;
    int* eoff   = ib;                  // 30004
    int* ecur   = ib + 30004;          // 30004
    int* voff   = ib + 60008;          // 100004
    int* vcur   = ib + 160012;         // 100004
    p += (size_t)260016 * 4;
    int* evlist = (int*)p;             p += (size_t)N_PAIRS * 4;
    int* velist = (int*)p;

    // zero counters (ecur, vcur; eoff/voff harmlessly included)
    hipMemsetAsync(ib, 0, (size_t)260016 * 4, stream);

    prelude_kernel<<<(N_PAIRS + 255) / 256, 256, 0, stream>>>(
        edges, vertex, X, Xbf, ecur, vcur);

    scan2_kernel<<<2, 1024, 0, stream>>>(ecur, eoff, vcur, voff);

    fill_xcd_kernel<<<8 * NG, 256, 0, stream>>>(edges, vertex, ecur, vcur,
                                                evlist, velist);

    edge_gather_kernel<<<EDGE_NUM / 4, 256, 0, stream>>>(
        Xbf, degV, Ww, Wb, eoff, evlist, Xe);

    vertex_gather_kernel<<<N_NODES / 4, 256, 0, stream>>>(
        X, Ww, Wb, Xe, voff, velist, out);
}